// Round 20
// baseline (36.198 us; speedup 1.0000x reference)
//
#include <hip/hip_runtime.h>
#include <math.h>

#define NROWS 8192
#define DIN   256
#define NH    8
#define NC    128
#define DOUT  256

typedef unsigned short ushort_t;
typedef __attribute__((ext_vector_type(8))) short bf16x8;
typedef __attribute__((ext_vector_type(8))) _Float16 f16x8;
typedef __attribute__((ext_vector_type(4))) float f32x4;

static __device__ __forceinline__ ushort_t f2bf(float f) {
  union { float f; unsigned u; } v; v.f = f;
  unsigned r = v.u + 0x7fffu + ((v.u >> 16) & 1u);
  return (ushort_t)(r >> 16);
}
static __device__ __forceinline__ float bf2f(ushort_t h) {
  union { unsigned u; float f; } v; v.u = ((unsigned)h) << 16;
  return v.f;
}

#define MFMA16(a, b, c) __builtin_amdgcn_mfma_f32_16x16x32_bf16((a), (b), (c), 0, 0, 0)
#define MFMA16F(a, b, c) __builtin_amdgcn_mfma_f32_16x16x32_f16((a), (b), (c), 0, 0, 0)
#define GLOAD_LDS16(g, l)                                                     \
  __builtin_amdgcn_global_load_lds(                                           \
      (const __attribute__((address_space(1))) void*)(g),                     \
      (__attribute__((address_space(3))) void*)(l), 16, 0, 0)

// ---------------------------------------------------------------------------
// Merged prep — byte-identical to r19.
// ---------------------------------------------------------------------------
__global__ __launch_bounds__(256) void prep_kernel(
    const float* __restrict__ Wq, const float* __restrict__ ctrs,
    const float* __restrict__ Wo, const float* __restrict__ Wv,
    const float* __restrict__ Ov, _Float16* __restrict__ wq16,
    _Float16* __restrict__ ctr16, float* __restrict__ cbias,
    ushort_t* __restrict__ WoT, ushort_t* __restrict__ W2bT) {
  int bid = blockIdx.x;
  int t = threadIdx.x;
  if (bid < 512) {
    int j = bid, k = t;
    int h = j >> 6, p = j & 63;
    float v = Wq[((size_t)k * 64 + p) * 8 + h];
    wq16[(size_t)j * 256 + k] = (_Float16)v;
  } else if (bid < 768) {
    int idx = (bid - 512) * 4 + (t >> 6);   // h*128+c
    int p = t & 63;
    float v = ctrs[(size_t)idx * 64 + p];
    float sq = v * v;
    #pragma unroll
    for (int off = 32; off >= 1; off >>= 1) sq += __shfl_xor(sq, off, 64);
    if (p == 0) cbias[idx] = -sq;
    ctr16[(size_t)idx * 64 + p] = (_Float16)v;
  } else if (bid < 1280) {
    int k = bid - 768;    // 0..511
    int n = t;            // 0..255
    WoT[(size_t)n * 512 + k] = f2bf(Wo[(size_t)k * 256 + n]);
  } else {
    int b = (bid - 1280) * 4 + (t >> 6);   // h*128 + c
    int p = t & 63;
    int h = b >> 7, c = b & 127;
    const float* wv = Wv + (size_t)b * 4096;
    float acc = 0.f;
    #pragma unroll 16
    for (int g = 0; g < 64; ++g) acc += wv[g * 64 + p];
    W2bT[((size_t)h * 128 + p) * 128 + c]      = f2bf(acc);
    W2bT[((size_t)h * 128 + 64 + p) * 128 + c] = f2bf(Ov[(size_t)b * 64 + p]);
  }
}

// ---------------------------------------------------------------------------
// gemm2 v3: BM=32 BN=64, 1024 blocks (4/CU), double-buffered LDS with the
// T3-minimum pattern: issue next tile's global_load_lds BEFORE computing the
// current tile; one {vmcnt(0)+lgkmcnt(0); barrier} per tile (8 barriers, was
// 16) so next-tile load latency hides under current ds_read+MFMA.
// k ascending, per-output MFMA order unchanged -> bit-identical output.
// ---------------------------------------------------------------------------
__global__ __launch_bounds__(256) void gemm2_kernel(
    const ushort_t* __restrict__ A, const ushort_t* __restrict__ Bt,
    float* __restrict__ out) {
  __shared__ ushort_t At[2][32 * 64];
  __shared__ ushort_t Bl[2][64 * 64];
  const int t = threadIdx.x;
  const int w = t >> 6, l = t & 63;
  const int wr = w >> 1, wc = w & 1;
  const int m0 = (blockIdx.x >> 2) * 32, n0 = (blockIdx.x & 3) * 64;
  const int lr = l & 15, lk = l >> 4;

#define STAGE_G(BUF, K0)                                                      \
  {                                                                           \
    {                                                                         \
      int q = w * 64 + l;                                                     \
      int row = q >> 3, s = q & 7;                                            \
      int kl = (K0) + ((s ^ (row & 7)) << 3);                                 \
      GLOAD_LDS16(A + (size_t)(m0 + row) * 512 + kl,                          \
                  (char*)At[BUF] + (size_t)w * 1024);                         \
    }                                                                         \
    _Pragma("unroll")                                                         \
    for (int i = 0; i < 2; ++i) {                                             \
      int q = (i * 4 + w) * 64 + l;                                           \
      int row = q >> 3, s = q & 7;                                            \
      int kl = (K0) + ((s ^ (row & 7)) << 3);                                 \
      GLOAD_LDS16(Bt + (size_t)(n0 + row) * 512 + kl,                         \
                  (char*)Bl[BUF] + (size_t)(i * 4 + w) * 1024);               \
    }                                                                         \
  }

#define MFMA_G(BUF)                                                           \
  {                                                                           \
    _Pragma("unroll")                                                         \
    for (int kk = 0; kk < 2; ++kk) {                                          \
      int rowa = wr * 16 + lr;                                                \
      int sa = (kk * 4 + lk) ^ (rowa & 7);                                    \
      bf16x8 af =                                                             \
          *(const bf16x8*)((const char*)At[BUF] + rowa * 128 + sa * 16);      \
      _Pragma("unroll")                                                       \
      for (int b = 0; b < 2; ++b) {                                           \
        int row = wc * 32 + b * 16 + lr;                                      \
        int s = (kk * 4 + lk) ^ (row & 7);                                    \
        bf16x8 bfr =                                                          \
            *(const bf16x8*)((const char*)Bl[BUF] + row * 128 + s * 16);      \
        acc[b] = MFMA16(af, bfr, acc[b]);                                     \
      }                                                                       \
    }                                                                         \
  }

#define G_WAITALL_BAR()                                                       \
  {                                                                           \
    asm volatile("s_waitcnt vmcnt(0) lgkmcnt(0)" ::: "memory");               \
    __builtin_amdgcn_sched_barrier(0);                                        \
    __builtin_amdgcn_s_barrier();                                             \
    __builtin_amdgcn_sched_barrier(0);                                        \
  }

  f32x4 acc[2];
  #pragma unroll
  for (int b = 0; b < 2; ++b) acc[b] = (f32x4){0.f, 0.f, 0.f, 0.f};

  STAGE_G(0, 0);
  G_WAITALL_BAR();
  #pragma unroll
  for (int kt = 0; kt < 4; ++kt) {
    // even tile (k = kt*128): compute buf0, prefetch buf1
    STAGE_G(1, kt * 128 + 64);
    MFMA_G(0);
    G_WAITALL_BAR();
    // odd tile (k = kt*128+64): compute buf1, prefetch buf0
    if (kt < 3) STAGE_G(0, kt * 128 + 128);
    MFMA_G(1);
    G_WAITALL_BAR();
  }

  #pragma unroll
  for (int b = 0; b < 2; ++b) {
    #pragma unroll
    for (int r = 0; r < 4; ++r) {
      int rowg = m0 + wr * 16 + lk * 4 + r;
      int colg = n0 + wc * 32 + b * 16 + lr;
      out[(size_t)rowg * 256 + colg] = acc[b][r];
    }
  }
#undef STAGE_G
#undef MFMA_G
#undef G_WAITALL_BAR
}

// ---------------------------------------------------------------------------
// Fused-pair v6 (f16 front-end) — byte-identical to r19.
// ---------------------------------------------------------------------------
__global__ __launch_bounds__(512, 4) void fused_pair_kernel(
    const float* __restrict__ x,          // [8192][256] f32
    const _Float16* __restrict__ wq16,    // [512][256]
    const _Float16* __restrict__ ctr16,   // [1024][64]
    const float* __restrict__ cbias,      // [1024]
    const ushort_t* __restrict__ W2bT,    // [1024][128]
    ushort_t* __restrict__ ho2) {         // flat (h,N,p)
  __shared__ __align__(16) char Au_raw[34816];   // [128][136] x 2B
  __shared__ char B0lds[16384];
  __shared__ char B1lds[16384];
  __shared__ float cb_lds[128];

  _Float16* Axf = (_Float16*)Au_raw;             // [128][136] (cols 0..127)
  _Float16* A1f = (_Float16*)Au_raw;             // [128][136] (cols 0..63)
  ushort_t* A2  = (ushort_t*)Au_raw;             // [128][136] (cols 0..127)

  const int t = threadIdx.x;
  const int w = t >> 6, l = t & 63;              // w in 0..7
  const int lr = l & 15, lk = l >> 4;
  const int h = blockIdx.x >> 6;                 // 8 heads x 64 pairs
  const int n0 = (blockIdx.x & 63) * 128;

#define STAGE_WQ2(BUF, KC2)                                                   \
  {                                                                           \
    _Pragma("unroll")                                                         \
    for (int i = 0; i < 2; ++i) {                                             \
      int q = (i * 8 + w) * 64 + l;       /* 0..1023 */                       \
      int jrow = q >> 4, s16 = q & 15;                                        \
      int c2 = s16 >> 3, s = s16 & 7;                                         \
      GLOAD_LDS16(wq16 + (size_t)(h * 64 + jrow) * 256 + (KC2) * 128 +        \
                      c2 * 64 + ((s ^ (jrow & 7)) << 3),                      \
                  (char*)(BUF) + (size_t)q * 16);                             \
    }                                                                         \
  }

#define STAGE_B128(BUF, SRC, LDB, KOFF)                                       \
  {                                                                           \
    _Pragma("unroll")                                                         \
    for (int i = 0; i < 2; ++i) {                                             \
      int q = (i * 8 + w) * 64 + l;       /* 0..1023 */                       \
      int row = q >> 3, s = q & 7;                                            \
      GLOAD_LDS16((SRC) + (size_t)(h * 128 + row) * (LDB) + (KOFF) +          \
                      ((s ^ (row & 7)) << 3),                                 \
                  (char*)(BUF) + (size_t)q * 16);                             \
    }                                                                         \
  }

#define MFMAX(BUF)                                                            \
  {                                                                           \
    _Pragma("unroll")                                                         \
    for (int c2 = 0; c2 < 2; ++c2) {                                          \
      _Pragma("unroll")                                                       \
      for (int kk = 0; kk < 2; ++kk) {                                        \
        f16x8 af = *(const f16x8*)&Axf[(w * 16 + lr) * 136 + c2 * 64 +        \
                                       kk * 32 + lk * 8];                     \
        _Pragma("unroll")                                                     \
        for (int cj = 0; cj < 4; ++cj) {                                      \
          int rh = cj * 16 + lr;                                              \
          int slot = (kk * 4 + lk) ^ (rh & 7);                                \
          f16x8 bfr = *(const f16x8*)((const char*)(BUF) + rh * 256 +         \
                                      c2 * 128 + slot * 16);                  \
          acc_x[cj] = MFMA16F(af, bfr, acc_x[cj]);                            \
        }                                                                     \
      }                                                                       \
    }                                                                         \
  }

#define MFMA_L(BUF, ACC)                                                      \
  {                                                                           \
    _Pragma("unroll")                                                         \
    for (int kk = 0; kk < 2; ++kk) {                                          \
      f16x8 af = *(const f16x8*)&A1f[(w * 16 + lr) * 136 + kk * 32 + lk * 8]; \
      _Pragma("unroll")                                                       \
      for (int cj = 0; cj < 8; ++cj) {                                        \
        int brow = cj * 16 + lr;                                              \
        int slot = (kk * 4 + lk) ^ (brow & 7);                                \
        f16x8 bfr =                                                           \
            *(const f16x8*)((const char*)(BUF) + brow * 128 + slot * 16);     \
        (ACC)[cj] = MFMA16F(af, bfr, (ACC)[cj]);                              \
      }                                                                       \
    }                                                                         \
  }

#define MFMA_T(BUF, ACC, KB)                                                  \
  {                                                                           \
    _Pragma("unroll")                                                         \
    for (int kk = 0; kk < 2; ++kk) {                                          \
      bf16x8 af = *(const bf16x8*)&A2[(w * 16 + lr) * 136 + (KB) + kk * 32 +  \
                                      lk * 8];                                \
      _Pragma("unroll")                                                       \
      for (int cj = 0; cj < 8; ++cj) {                                        \
        int brow = cj * 16 + lr;                                              \
        int slot = (kk * 4 + lk) ^ (brow & 7);                                \
        bf16x8 bfr =                                                          \
            *(const bf16x8*)((const char*)(BUF) + brow * 128 + slot * 16);    \
        (ACC)[cj] = MFMA16(af, bfr, (ACC)[cj]);                               \
      }                                                                       \
    }                                                                         \
  }

#define BAR() __builtin_amdgcn_s_barrier()
#define SCHED() __builtin_amdgcn_sched_barrier(0)
#define WAITALL_BAR()                                                         \
  {                                                                           \
    asm volatile("s_waitcnt vmcnt(0) lgkmcnt(0)" ::: "memory");               \
    SCHED(); BAR(); SCHED();                                                  \
  }

  const int xrow = t >> 2;                 // 0..127 (wave w: rows 16w..16w+15)
  const int xsegf = (t & 3) << 4;          // 0/16/32/48 (floats within chunk)
  const float* xb = x + (size_t)(n0 + xrow) * 256 + xsegf;
  float4 xr[8];

#define LOAD_X2(KC2)                                                          \
  {                                                                           \
    _Pragma("unroll")                                                         \
    for (int c2 = 0; c2 < 2; ++c2)                                            \
      _Pragma("unroll")                                                       \
      for (int j = 0; j < 4; ++j)                                             \
        xr[c2 * 4 + j] =                                                      \
            *(const float4*)(xb + (KC2) * 128 + c2 * 64 + j * 4);             \
  }

#define CVT_AX2()                                                             \
  {                                                                           \
    _Pragma("unroll")                                                         \
    for (int c2 = 0; c2 < 2; ++c2) {                                          \
      f16x8 h0, h1;                                                           \
      float f0[8] = {xr[c2*4].x,   xr[c2*4].y,   xr[c2*4].z,   xr[c2*4].w,    \
                     xr[c2*4+1].x, xr[c2*4+1].y, xr[c2*4+1].z, xr[c2*4+1].w}; \
      float f1[8] = {xr[c2*4+2].x, xr[c2*4+2].y, xr[c2*4+2].z, xr[c2*4+2].w,  \
                     xr[c2*4+3].x, xr[c2*4+3].y, xr[c2*4+3].z, xr[c2*4+3].w}; \
      _Pragma("unroll")                                                       \
      for (int e = 0; e < 8; ++e) { h0[e] = (_Float16)f0[e];                  \
                                    h1[e] = (_Float16)f1[e]; }                \
      *(f16x8*)&Axf[xrow * 136 + c2 * 64 + xsegf]     = h0;                   \
      *(f16x8*)&Axf[xrow * 136 + c2 * 64 + xsegf + 8] = h1;                   \
    }                                                                         \
  }

  // ---- Prologue ----
  cb_lds[t & 127] = cbias[h * 128 + (t & 127)];
  STAGE_WQ2(B0lds, 0);
  LOAD_X2(0);
  f32x4 acc_x[4];
  #pragma unroll
  for (int cj = 0; cj < 4; ++cj) acc_x[cj] = (f32x4){0.f, 0.f, 0.f, 0.f};
  CVT_AX2();
  WAITALL_BAR();                           // B0 (Wq chunks 0-1) ready

  // ---- R0: xin chunks 0-1; stage Wq 2-3; load/cvt x 2-3 ----
  STAGE_WQ2(B1lds, 1);
  LOAD_X2(1);
  MFMAX(B0lds);
  CVT_AX2();                               // own-band, after own reads
  WAITALL_BAR();
  // ---- R1: xin chunks 2-3; stage ctr; write A1 (f16, own band) ----
  STAGE_B128(B0lds, ctr16, 64, 0);
  MFMAX(B1lds);
  #pragma unroll
  for (int cj = 0; cj < 4; ++cj) {
    #pragma unroll
    for (int r = 0; r < 4; ++r) {
      int row = w * 16 + lk * 4 + r;
      A1f[row * 136 + cj * 16 + lr] = (_Float16)acc_x[cj][r];
    }
  }
  WAITALL_BAR();
  // ---- R2: logits + softmax; stage W2 k0 ----
  STAGE_B128(B1lds, W2bT, 128, 0);
  f32x4 acc[8];
  #pragma unroll
  for (int cj = 0; cj < 8; ++cj) acc[cj] = (f32x4){0.f, 0.f, 0.f, 0.f};
  MFMA_L(B0lds, acc);
  {
    float cbv[8];
    #pragma unroll
    for (int cj = 0; cj < 8; ++cj) cbv[cj] = cb_lds[cj * 16 + lr];
    #pragma unroll
    for (int r = 0; r < 4; ++r) {
      float v[8];
      float m = -1e30f;
      #pragma unroll
      for (int cj = 0; cj < 8; ++cj) {
        v[cj] = 2.f * acc[cj][r] + cbv[cj];
        m = fmaxf(m, v[cj]);
      }
      m = fmaxf(m, __shfl_xor(m, 1, 64));
      m = fmaxf(m, __shfl_xor(m, 2, 64));
      m = fmaxf(m, __shfl_xor(m, 4, 64));
      m = fmaxf(m, __shfl_xor(m, 8, 64));
      float s = 0.f;
      #pragma unroll
      for (int cj = 0; cj < 8; ++cj) {
        v[cj] = __expf(v[cj] - m);
        s += v[cj];
      }
      s += __shfl_xor(s, 1, 64);
      s += __shfl_xor(s, 2, 64);
      s += __shfl_xor(s, 4, 64);
      s += __shfl_xor(s, 8, 64);
      float inv = 1.f / s;
      int row = w * 16 + lk * 4 + r;
      #pragma unroll
      for (int cj = 0; cj < 8; ++cj)
        A2[row * 136 + cj * 16 + lr] = f2bf(v[cj] * inv);
    }
  }
  WAITALL_BAR();
  // ---- R3: T0; stage W2 k64 ----
  STAGE_B128(B0lds, W2bT, 128, 64);
  f32x4 accT[8];
  #pragma unroll
  for (int cj = 0; cj < 8; ++cj) accT[cj] = (f32x4){0.f, 0.f, 0.f, 0.f};
  MFMA_T(B1lds, accT, 0);
  WAITALL_BAR();
  // ---- R4: T1 + epilogue ----
  MFMA_T(B0lds, accT, 64);
  #pragma unroll
  for (int cj = 0; cj < 4; ++cj) {
    #pragma unroll
    for (int r = 0; r < 4; ++r) {
      int row = w * 16 + lk * 4 + r;
      int p = cj * 16 + lr;
      float hov = acc_x[cj][r] * accT[cj][r] + accT[cj + 4][r];
      ((ushort_t*)B1lds)[row * 64 + p] = f2bf(hov);
    }
  }
  asm volatile("s_waitcnt lgkmcnt(0)" ::: "memory");
  SCHED(); BAR(); SCHED();
  #pragma unroll
  for (int i = 0; i < 2; ++i) {
    int q = i * 512 + t;
    int row = q >> 3, s = q & 7;
    uint4 v = *(const uint4*)((const char*)B1lds + row * 128 + s * 16);
    *(uint4*)(ho2 + ((size_t)h * NROWS + n0 + row) * 64 + s * 8) = v;
  }
#undef STAGE_WQ2
#undef STAGE_B128
#undef MFMAX
#undef MFMA_L
#undef MFMA_T
#undef BAR
#undef SCHED
#undef WAITALL_BAR
#undef LOAD_X2
#undef CVT_AX2
}

// ---------------------------------------------------------------------------
extern "C" void kernel_launch(void* const* d_in, const int* in_sizes, int n_in,
                              void* d_out, int out_size, void* d_ws, size_t ws_size,
                              hipStream_t stream) {
  (void)in_sizes; (void)n_in; (void)out_size; (void)ws_size;
  const float* x    = (const float*)d_in[0];
  const float* ctrs = (const float*)d_in[1];
  const float* Wv   = (const float*)d_in[2];
  const float* Ov   = (const float*)d_in[3];
  const float* Wq   = (const float*)d_in[4];
  const float* Wo   = (const float*)d_in[5];
  float* out = (float*)d_out;

  char* wsb = (char*)d_ws;
  _Float16* wq16  = (_Float16*)wsb;                   // [0, 262144)
  _Float16* ctr16 = (_Float16*)(wsb + 262144);        // [262144, 393216)
  float*    cb    = (float*)   (wsb + 393216);        // [393216, 397312)
  ushort_t* W2bT  = (ushort_t*)(wsb + 397312);        // [397312, 659456)
  ushort_t* WoT   = (ushort_t*)(wsb + 659456);        // [659456, 921600)
  ushort_t* ho2   = (ushort_t*)(wsb + 2097152);       // [2 MiB, 2 MiB + 8 MiB)

  prep_kernel<<<1536, 256, 0, stream>>>(Wq, ctrs, Wo, Wv, Ov,
                                        wq16, ctr16, cb, WoT, W2bT);
  fused_pair_kernel<<<512, 512, 0, stream>>>(x, wq16, ctr16, cb, W2bT, ho2);
  gemm2_kernel<<<1024, 256, 0, stream>>>(ho2, WoT, out);
}

// Round 21
// 35.018 us; speedup vs baseline: 1.0337x; 1.0337x over previous
//
#include <hip/hip_runtime.h>
#include <math.h>

#define NROWS 8192
#define DIN   256
#define NH    8
#define NC    128
#define DOUT  256

typedef unsigned short ushort_t;
typedef __attribute__((ext_vector_type(8))) short bf16x8;
typedef __attribute__((ext_vector_type(8))) _Float16 f16x8;
typedef __attribute__((ext_vector_type(4))) float f32x4;

static __device__ __forceinline__ ushort_t f2bf(float f) {
  union { float f; unsigned u; } v; v.f = f;
  unsigned r = v.u + 0x7fffu + ((v.u >> 16) & 1u);
  return (ushort_t)(r >> 16);
}
static __device__ __forceinline__ float bf2f(ushort_t h) {
  union { unsigned u; float f; } v; v.u = ((unsigned)h) << 16;
  return v.f;
}

#define MFMA16(a, b, c) __builtin_amdgcn_mfma_f32_16x16x32_bf16((a), (b), (c), 0, 0, 0)
#define MFMA16F(a, b, c) __builtin_amdgcn_mfma_f32_16x16x32_f16((a), (b), (c), 0, 0, 0)
#define GLOAD_LDS16(g, l)                                                     \
  __builtin_amdgcn_global_load_lds(                                           \
      (const __attribute__((address_space(1))) void*)(g),                     \
      (__attribute__((address_space(3))) void*)(l), 16, 0, 0)

// ---------------------------------------------------------------------------
// Merged prep — byte-identical to r19.
// ---------------------------------------------------------------------------
__global__ __launch_bounds__(256) void prep_kernel(
    const float* __restrict__ Wq, const float* __restrict__ ctrs,
    const float* __restrict__ Wo, const float* __restrict__ Wv,
    const float* __restrict__ Ov, _Float16* __restrict__ wq16,
    _Float16* __restrict__ ctr16, float* __restrict__ cbias,
    ushort_t* __restrict__ WoT, ushort_t* __restrict__ W2bT) {
  int bid = blockIdx.x;
  int t = threadIdx.x;
  if (bid < 512) {
    int j = bid, k = t;
    int h = j >> 6, p = j & 63;
    float v = Wq[((size_t)k * 64 + p) * 8 + h];
    wq16[(size_t)j * 256 + k] = (_Float16)v;
  } else if (bid < 768) {
    int idx = (bid - 512) * 4 + (t >> 6);   // h*128+c
    int p = t & 63;
    float v = ctrs[(size_t)idx * 64 + p];
    float sq = v * v;
    #pragma unroll
    for (int off = 32; off >= 1; off >>= 1) sq += __shfl_xor(sq, off, 64);
    if (p == 0) cbias[idx] = -sq;
    ctr16[(size_t)idx * 64 + p] = (_Float16)v;
  } else if (bid < 1280) {
    int k = bid - 768;    // 0..511
    int n = t;            // 0..255
    WoT[(size_t)n * 512 + k] = f2bf(Wo[(size_t)k * 256 + n]);
  } else {
    int b = (bid - 1280) * 4 + (t >> 6);   // h*128 + c
    int p = t & 63;
    int h = b >> 7, c = b & 127;
    const float* wv = Wv + (size_t)b * 4096;
    float acc = 0.f;
    #pragma unroll 16
    for (int g = 0; g < 64; ++g) acc += wv[g * 64 + p];
    W2bT[((size_t)h * 128 + p) * 128 + c]      = f2bf(acc);
    W2bT[((size_t)h * 128 + 64 + p) * 128 + c] = f2bf(Ov[(size_t)b * 64 + p]);
  }
}

// ---------------------------------------------------------------------------
// gemm2 — r15/r19 proven version (BM=32, 1024 blocks, 4/CU, single-buffer).
// ---------------------------------------------------------------------------
__global__ __launch_bounds__(256) void gemm2_kernel(
    const ushort_t* __restrict__ A, const ushort_t* __restrict__ Bt,
    float* __restrict__ out) {
  __shared__ ushort_t At[32 * 64];
  __shared__ ushort_t Bl[64 * 64];
  const int t = threadIdx.x;
  const int w = t >> 6, l = t & 63;
  const int wr = w >> 1, wc = w & 1;
  const int m0 = (blockIdx.x >> 2) * 32, n0 = (blockIdx.x & 3) * 64;
  const int lr = l & 15, lk = l >> 4;

  f32x4 acc[2];
  #pragma unroll
  for (int b = 0; b < 2; ++b) acc[b] = (f32x4){0.f, 0.f, 0.f, 0.f};

  for (int k0 = 0; k0 < 512; k0 += 64) {
    {
      int q = w * 64 + l;
      int row = q >> 3, s = q & 7;
      int kl = k0 + ((s ^ (row & 7)) << 3);
      GLOAD_LDS16(A + (size_t)(m0 + row) * 512 + kl,
                  (char*)At + (size_t)w * 1024);
    }
    #pragma unroll
    for (int i = 0; i < 2; ++i) {
      int q = (i * 4 + w) * 64 + l;
      int row = q >> 3, s = q & 7;
      int kl = k0 + ((s ^ (row & 7)) << 3);
      GLOAD_LDS16(Bt + (size_t)(n0 + row) * 512 + kl,
                  (char*)Bl + (size_t)(i * 4 + w) * 1024);
    }
    __syncthreads();
    #pragma unroll
    for (int kk = 0; kk < 2; ++kk) {
      int rowa = wr * 16 + lr;
      int sa = (kk * 4 + lk) ^ (rowa & 7);
      bf16x8 af = *(const bf16x8*)((const char*)At + rowa * 128 + sa * 16);
      #pragma unroll
      for (int b = 0; b < 2; ++b) {
        int row = wc * 32 + b * 16 + lr;
        int s = (kk * 4 + lk) ^ (row & 7);
        bf16x8 bfr = *(const bf16x8*)((const char*)Bl + row * 128 + s * 16);
        acc[b] = MFMA16(af, bfr, acc[b]);
      }
    }
    __syncthreads();
  }
  #pragma unroll
  for (int b = 0; b < 2; ++b) {
    #pragma unroll
    for (int r = 0; r < 4; ++r) {
      int rowg = m0 + wr * 16 + lk * 4 + r;
      int colg = n0 + wc * 32 + b * 16 + lr;
      out[(size_t)rowg * 256 + colg] = acc[b][r];
    }
  }
}

// ---------------------------------------------------------------------------
// Fused-pair v6 (f16 front-end) — byte-identical to r19.
// ---------------------------------------------------------------------------
__global__ __launch_bounds__(512, 4) void fused_pair_kernel(
    const float* __restrict__ x,          // [8192][256] f32
    const _Float16* __restrict__ wq16,    // [512][256]
    const _Float16* __restrict__ ctr16,   // [1024][64]
    const float* __restrict__ cbias,      // [1024]
    const ushort_t* __restrict__ W2bT,    // [1024][128]
    ushort_t* __restrict__ ho2) {         // flat (h,N,p)
  __shared__ __align__(16) char Au_raw[34816];   // [128][136] x 2B
  __shared__ char B0lds[16384];
  __shared__ char B1lds[16384];
  __shared__ float cb_lds[128];

  _Float16* Axf = (_Float16*)Au_raw;             // [128][136] (cols 0..127)
  _Float16* A1f = (_Float16*)Au_raw;             // [128][136] (cols 0..63)
  ushort_t* A2  = (ushort_t*)Au_raw;             // [128][136] (cols 0..127)

  const int t = threadIdx.x;
  const int w = t >> 6, l = t & 63;              // w in 0..7
  const int lr = l & 15, lk = l >> 4;
  const int h = blockIdx.x >> 6;                 // 8 heads x 64 pairs
  const int n0 = (blockIdx.x & 63) * 128;

#define STAGE_WQ2(BUF, KC2)                                                   \
  {                                                                           \
    _Pragma("unroll")                                                         \
    for (int i = 0; i < 2; ++i) {                                             \
      int q = (i * 8 + w) * 64 + l;       /* 0..1023 */                       \
      int jrow = q >> 4, s16 = q & 15;                                        \
      int c2 = s16 >> 3, s = s16 & 7;                                         \
      GLOAD_LDS16(wq16 + (size_t)(h * 64 + jrow) * 256 + (KC2) * 128 +        \
                      c2 * 64 + ((s ^ (jrow & 7)) << 3),                      \
                  (char*)(BUF) + (size_t)q * 16);                             \
    }                                                                         \
  }

#define STAGE_B128(BUF, SRC, LDB, KOFF)                                       \
  {                                                                           \
    _Pragma("unroll")                                                         \
    for (int i = 0; i < 2; ++i) {                                             \
      int q = (i * 8 + w) * 64 + l;       /* 0..1023 */                       \
      int row = q >> 3, s = q & 7;                                            \
      GLOAD_LDS16((SRC) + (size_t)(h * 128 + row) * (LDB) + (KOFF) +          \
                      ((s ^ (row & 7)) << 3),                                 \
                  (char*)(BUF) + (size_t)q * 16);                             \
    }                                                                         \
  }

#define MFMAX(BUF)                                                            \
  {                                                                           \
    _Pragma("unroll")                                                         \
    for (int c2 = 0; c2 < 2; ++c2) {                                          \
      _Pragma("unroll")                                                       \
      for (int kk = 0; kk < 2; ++kk) {                                        \
        f16x8 af = *(const f16x8*)&Axf[(w * 16 + lr) * 136 + c2 * 64 +        \
                                       kk * 32 + lk * 8];                     \
        _Pragma("unroll")                                                     \
        for (int cj = 0; cj < 4; ++cj) {                                      \
          int rh = cj * 16 + lr;                                              \
          int slot = (kk * 4 + lk) ^ (rh & 7);                                \
          f16x8 bfr = *(const f16x8*)((const char*)(BUF) + rh * 256 +         \
                                      c2 * 128 + slot * 16);                  \
          acc_x[cj] = MFMA16F(af, bfr, acc_x[cj]);                            \
        }                                                                     \
      }                                                                       \
    }                                                                         \
  }

#define MFMA_L(BUF, ACC)                                                      \
  {                                                                           \
    _Pragma("unroll")                                                         \
    for (int kk = 0; kk < 2; ++kk) {                                          \
      f16x8 af = *(const f16x8*)&A1f[(w * 16 + lr) * 136 + kk * 32 + lk * 8]; \
      _Pragma("unroll")                                                       \
      for (int cj = 0; cj < 8; ++cj) {                                        \
        int brow = cj * 16 + lr;                                              \
        int slot = (kk * 4 + lk) ^ (brow & 7);                                \
        f16x8 bfr =                                                           \
            *(const f16x8*)((const char*)(BUF) + brow * 128 + slot * 16);     \
        (ACC)[cj] = MFMA16F(af, bfr, (ACC)[cj]);                              \
      }                                                                       \
    }                                                                         \
  }

#define MFMA_T(BUF, ACC, KB)                                                  \
  {                                                                           \
    _Pragma("unroll")                                                         \
    for (int kk = 0; kk < 2; ++kk) {                                          \
      bf16x8 af = *(const bf16x8*)&A2[(w * 16 + lr) * 136 + (KB) + kk * 32 +  \
                                      lk * 8];                                \
      _Pragma("unroll")                                                       \
      for (int cj = 0; cj < 8; ++cj) {                                        \
        int brow = cj * 16 + lr;                                              \
        int slot = (kk * 4 + lk) ^ (brow & 7);                                \
        bf16x8 bfr =                                                          \
            *(const bf16x8*)((const char*)(BUF) + brow * 128 + slot * 16);    \
        (ACC)[cj] = MFMA16(af, bfr, (ACC)[cj]);                               \
      }                                                                       \
    }                                                                         \
  }

#define BAR() __builtin_amdgcn_s_barrier()
#define SCHED() __builtin_amdgcn_sched_barrier(0)
#define WAITALL_BAR()                                                         \
  {                                                                           \
    asm volatile("s_waitcnt vmcnt(0) lgkmcnt(0)" ::: "memory");               \
    SCHED(); BAR(); SCHED();                                                  \
  }

  const int xrow = t >> 2;                 // 0..127 (wave w: rows 16w..16w+15)
  const int xsegf = (t & 3) << 4;          // 0/16/32/48 (floats within chunk)
  const float* xb = x + (size_t)(n0 + xrow) * 256 + xsegf;
  float4 xr[8];

#define LOAD_X2(KC2)                                                          \
  {                                                                           \
    _Pragma("unroll")                                                         \
    for (int c2 = 0; c2 < 2; ++c2)                                            \
      _Pragma("unroll")                                                       \
      for (int j = 0; j < 4; ++j)                                             \
        xr[c2 * 4 + j] =                                                      \
            *(const float4*)(xb + (KC2) * 128 + c2 * 64 + j * 4);             \
  }

#define CVT_AX2()                                                             \
  {                                                                           \
    _Pragma("unroll")                                                         \
    for (int c2 = 0; c2 < 2; ++c2) {                                          \
      f16x8 h0, h1;                                                           \
      float f0[8] = {xr[c2*4].x,   xr[c2*4].y,   xr[c2*4].z,   xr[c2*4].w,    \
                     xr[c2*4+1].x, xr[c2*4+1].y, xr[c2*4+1].z, xr[c2*4+1].w}; \
      float f1[8] = {xr[c2*4+2].x, xr[c2*4+2].y, xr[c2*4+2].z, xr[c2*4+2].w,  \
                     xr[c2*4+3].x, xr[c2*4+3].y, xr[c2*4+3].z, xr[c2*4+3].w}; \
      _Pragma("unroll")                                                       \
      for (int e = 0; e < 8; ++e) { h0[e] = (_Float16)f0[e];                  \
                                    h1[e] = (_Float16)f1[e]; }                \
      *(f16x8*)&Axf[xrow * 136 + c2 * 64 + xsegf]     = h0;                   \
      *(f16x8*)&Axf[xrow * 136 + c2 * 64 + xsegf + 8] = h1;                   \
    }                                                                         \
  }

  // ---- Prologue ----
  cb_lds[t & 127] = cbias[h * 128 + (t & 127)];
  STAGE_WQ2(B0lds, 0);
  LOAD_X2(0);
  f32x4 acc_x[4];
  #pragma unroll
  for (int cj = 0; cj < 4; ++cj) acc_x[cj] = (f32x4){0.f, 0.f, 0.f, 0.f};
  CVT_AX2();
  WAITALL_BAR();                           // B0 (Wq chunks 0-1) ready

  // ---- R0: xin chunks 0-1; stage Wq 2-3; load/cvt x 2-3 ----
  STAGE_WQ2(B1lds, 1);
  LOAD_X2(1);
  MFMAX(B0lds);
  CVT_AX2();                               // own-band, after own reads
  WAITALL_BAR();
  // ---- R1: xin chunks 2-3; stage ctr; write A1 (f16, own band) ----
  STAGE_B128(B0lds, ctr16, 64, 0);
  MFMAX(B1lds);
  #pragma unroll
  for (int cj = 0; cj < 4; ++cj) {
    #pragma unroll
    for (int r = 0; r < 4; ++r) {
      int row = w * 16 + lk * 4 + r;
      A1f[row * 136 + cj * 16 + lr] = (_Float16)acc_x[cj][r];
    }
  }
  WAITALL_BAR();
  // ---- R2: logits + softmax; stage W2 k0 ----
  STAGE_B128(B1lds, W2bT, 128, 0);
  f32x4 acc[8];
  #pragma unroll
  for (int cj = 0; cj < 8; ++cj) acc[cj] = (f32x4){0.f, 0.f, 0.f, 0.f};
  MFMA_L(B0lds, acc);
  {
    float cbv[8];
    #pragma unroll
    for (int cj = 0; cj < 8; ++cj) cbv[cj] = cb_lds[cj * 16 + lr];
    #pragma unroll
    for (int r = 0; r < 4; ++r) {
      float v[8];
      float m = -1e30f;
      #pragma unroll
      for (int cj = 0; cj < 8; ++cj) {
        v[cj] = 2.f * acc[cj][r] + cbv[cj];
        m = fmaxf(m, v[cj]);
      }
      m = fmaxf(m, __shfl_xor(m, 1, 64));
      m = fmaxf(m, __shfl_xor(m, 2, 64));
      m = fmaxf(m, __shfl_xor(m, 4, 64));
      m = fmaxf(m, __shfl_xor(m, 8, 64));
      float s = 0.f;
      #pragma unroll
      for (int cj = 0; cj < 8; ++cj) {
        v[cj] = __expf(v[cj] - m);
        s += v[cj];
      }
      s += __shfl_xor(s, 1, 64);
      s += __shfl_xor(s, 2, 64);
      s += __shfl_xor(s, 4, 64);
      s += __shfl_xor(s, 8, 64);
      float inv = 1.f / s;
      int row = w * 16 + lk * 4 + r;
      #pragma unroll
      for (int cj = 0; cj < 8; ++cj)
        A2[row * 136 + cj * 16 + lr] = f2bf(v[cj] * inv);
    }
  }
  WAITALL_BAR();
  // ---- R3: T0; stage W2 k64 ----
  STAGE_B128(B0lds, W2bT, 128, 64);
  f32x4 accT[8];
  #pragma unroll
  for (int cj = 0; cj < 8; ++cj) accT[cj] = (f32x4){0.f, 0.f, 0.f, 0.f};
  MFMA_T(B1lds, accT, 0);
  WAITALL_BAR();
  // ---- R4: T1 + epilogue ----
  MFMA_T(B0lds, accT, 64);
  #pragma unroll
  for (int cj = 0; cj < 4; ++cj) {
    #pragma unroll
    for (int r = 0; r < 4; ++r) {
      int row = w * 16 + lk * 4 + r;
      int p = cj * 16 + lr;
      float hov = acc_x[cj][r] * accT[cj][r] + accT[cj + 4][r];
      ((ushort_t*)B1lds)[row * 64 + p] = f2bf(hov);
    }
  }
  asm volatile("s_waitcnt lgkmcnt(0)" ::: "memory");
  SCHED(); BAR(); SCHED();
  #pragma unroll
  for (int i = 0; i < 2; ++i) {
    int q = i * 512 + t;
    int row = q >> 3, s = q & 7;
    uint4 v = *(const uint4*)((const char*)B1lds + row * 128 + s * 16);
    *(uint4*)(ho2 + ((size_t)h * NROWS + n0 + row) * 64 + s * 8) = v;
  }
#undef STAGE_WQ2
#undef STAGE_B128
#undef MFMAX
#undef MFMA_L
#undef MFMA_T
#undef BAR
#undef SCHED
#undef WAITALL_BAR
#undef LOAD_X2
#undef CVT_AX2
}

// ---------------------------------------------------------------------------
extern "C" void kernel_launch(void* const* d_in, const int* in_sizes, int n_in,
                              void* d_out, int out_size, void* d_ws, size_t ws_size,
                              hipStream_t stream) {
  (void)in_sizes; (void)n_in; (void)out_size; (void)ws_size;
  const float* x    = (const float*)d_in[0];
  const float* ctrs = (const float*)d_in[1];
  const float* Wv   = (const float*)d_in[2];
  const float* Ov   = (const float*)d_in[3];
  const float* Wq   = (const float*)d_in[4];
  const float* Wo   = (const float*)d_in[5];
  float* out = (float*)d_out;

  char* wsb = (char*)d_ws;
  _Float16* wq16  = (_Float16*)wsb;                   // [0, 262144)
  _Float16* ctr16 = (_Float16*)(wsb + 262144);        // [262144, 393216)
  float*    cb    = (float*)   (wsb + 393216);        // [393216, 397312)
  ushort_t* W2bT  = (ushort_t*)(wsb + 397312);        // [397312, 659456)
  ushort_t* WoT   = (ushort_t*)(wsb + 659456);        // [659456, 921600)
  ushort_t* ho2   = (ushort_t*)(wsb + 2097152);       // [2 MiB, 2 MiB + 8 MiB)

  prep_kernel<<<1536, 256, 0, stream>>>(Wq, ctrs, Wo, Wv, Ov,
                                        wq16, ctr16, cb, WoT, W2bT);
  fused_pair_kernel<<<512, 512, 0, stream>>>(x, wq16, ctr16, cb, W2bT, ho2);
  gemm2_kernel<<<1024, 256, 0, stream>>>(ho2, WoT, out);
}